// Round 2
// baseline (662.714 us; speedup 1.0000x reference)
//
#include <hip/hip_runtime.h>
#include <hip/hip_fp16.h>

constexpr int HID = 128;
constexpr int NH  = 4;
constexpr int DH  = 64;

typedef _Float16 f16x2 __attribute__((ext_vector_type(2)));
struct F16x8 { f16x2 a, b, c, d; };   // 16 bytes

__device__ __forceinline__ float fdot2(f16x2 a, f16x2 b, float c) {
#if __has_builtin(__builtin_amdgcn_fdot2)
  return __builtin_amdgcn_fdot2(a, b, c, false);
#else
  return c + (float)a[0] * (float)b[0] + (float)a[1] * (float)b[1];
#endif
}

__device__ __forceinline__ f16x2 relu2(f16x2 x) {
  f16x2 z = {(_Float16)0, (_Float16)0};
#if __has_builtin(__builtin_elementwise_max)
  return __builtin_elementwise_max(x, z);
#else
  f16x2 r; r[0] = x[0] > z[0] ? x[0] : z[0]; r[1] = x[1] > z[1] ? x[1] : z[1]; return r;
#endif
}

// ---------------- uv precompute: u = feat @ W1_top, v = feat @ W1_bot ----------------
// writes into concatenated tables: u_cat[n*256 + roff + j], roff = 0 (pca) / 128 (pimg)
template<int F, int NB>
__launch_bounds__(256)
__global__ void uv_kernel(const float* __restrict__ feat, const float* __restrict__ w1,
                          _Float16* __restrict__ u_cat, _Float16* __restrict__ v_cat,
                          int roff, int N) {
  __shared__ float sfeat[NB][F + 1];
  int nb = blockIdx.x * NB;
  for (int i = threadIdx.x; i < NB * F; i += 256) {
    int n = i / F, k = i - n * F;
    int gn = nb + n;
    sfeat[n][k] = (gn < N) ? feat[(size_t)gn * F + k] : 0.f;
  }
  __syncthreads();
  int j = threadIdx.x & 127;
  int g = threadIdx.x >> 7;           // 0..1
  constexpr int NPT = NB / 2;
  float ua[NPT], va[NPT];
#pragma unroll
  for (int i = 0; i < NPT; i++) { ua[i] = 0.f; va[i] = 0.f; }
  for (int k = 0; k < F; k++) {
    float wu = w1[k * HID + j];
    float wv = w1[(F + k) * HID + j];
#pragma unroll
    for (int i = 0; i < NPT; i++) {
      float f = sfeat[g * NPT + i][k];
      ua[i] = fmaf(f, wu, ua[i]);
      va[i] = fmaf(f, wv, va[i]);
    }
  }
#pragma unroll
  for (int i = 0; i < NPT; i++) {
    int gn = nb + g * NPT + i;
    if (gn < N) {
      u_cat[(size_t)gn * 256 + roff + j] = (_Float16)ua[i];
      v_cat[(size_t)gn * 256 + roff + j] = (_Float16)va[i];
    }
  }
}

// ---------------- h -> fp16 copy ----------------
__global__ void h16_kernel(const float* __restrict__ h, _Float16* __restrict__ h16, int total) {
  int i = (blockIdx.x * 256 + threadIdx.x) * 4;
  if (i + 3 < total) {
    float4 v = *(const float4*)(h + i);
    h16[i] = (_Float16)v.x; h16[i + 1] = (_Float16)v.y;
    h16[i + 2] = (_Float16)v.z; h16[i + 3] = (_Float16)v.w;
  } else {
    for (int q = 0; q < 4; q++) if (i + q < total) h16[i + q] = (_Float16)h[i + q];
  }
}

// ---------------- CSR build ----------------
__global__ void count_kernel(const int* __restrict__ dst, int* __restrict__ counts, int E) {
  int e = blockIdx.x * 256 + threadIdx.x;
  if (e < E) atomicAdd(&counts[dst[e]], 1);
}

__launch_bounds__(256)
__global__ void scan1_kernel(const int* __restrict__ counts, int* __restrict__ bsums, int N) {
  int b = blockIdx.x, tid = threadIdx.x;
  int base = b * 1024 + tid * 4;
  int s = 0;
  if (base + 3 < N) {
    int4 v = *(const int4*)(counts + base);
    s = v.x + v.y + v.z + v.w;
  } else {
    for (int q = 0; q < 4; q++) { int idx = base + q; if (idx < N) s += counts[idx]; }
  }
#pragma unroll
  for (int o = 32; o >= 1; o >>= 1) s += __shfl_xor(s, o);
  __shared__ int ws[4];
  if ((tid & 63) == 0) ws[tid >> 6] = s;
  __syncthreads();
  if (tid == 0) bsums[b] = ws[0] + ws[1] + ws[2] + ws[3];
}

__launch_bounds__(1024)
__global__ void scan2_kernel(const int* __restrict__ bsums, int* __restrict__ bpre,
                             int* __restrict__ offsets, int NB, int N, int E) {
  int tid = threadIdx.x, lane = tid & 63, w = tid >> 6;
  int v = (tid < NB) ? bsums[tid] : 0;
  int incl = v;
#pragma unroll
  for (int o = 1; o < 64; o <<= 1) { int t = __shfl_up(incl, o); if (lane >= o) incl += t; }
  __shared__ int ws[16];
  if (lane == 63) ws[w] = incl;
  __syncthreads();
  int wpre = 0;
  for (int q = 0; q < w; q++) wpre += ws[q];
  if (tid < NB) bpre[tid] = wpre + incl - v;
  if (tid == 0) offsets[N] = E;
}

__launch_bounds__(256)
__global__ void scan3_kernel(const int* __restrict__ counts, const int* __restrict__ bpre,
                             int* __restrict__ offsets, int N) {
  int b = blockIdx.x, tid = threadIdx.x, lane = tid & 63, w = tid >> 6;
  int base = b * 1024 + tid * 4;
  int c[4] = {0, 0, 0, 0};
  if (base + 3 < N) {
    int4 v = *(const int4*)(counts + base);
    c[0] = v.x; c[1] = v.y; c[2] = v.z; c[3] = v.w;
  } else {
    for (int q = 0; q < 4; q++) { int idx = base + q; if (idx < N) c[q] = counts[idx]; }
  }
  int s = c[0] + c[1] + c[2] + c[3];
  int incl = s;
#pragma unroll
  for (int o = 1; o < 64; o <<= 1) { int t = __shfl_up(incl, o); if (lane >= o) incl += t; }
  int excl = incl - s;
  __shared__ int ws[4];
  if (lane == 63) ws[w] = incl;
  __syncthreads();
  int wpre = 0;
  for (int q = 0; q < w; q++) wpre += ws[q];
  int off = bpre[b] + wpre + excl;
  for (int q = 0; q < 4; q++) {
    int idx = base + q;
    if (idx < N) offsets[idx] = off;
    off += c[q];
  }
}

__global__ void fill_kernel(const int* __restrict__ src, const int* __restrict__ dst,
                            const int* __restrict__ offsets, int* __restrict__ cursor,
                            int* __restrict__ src_sorted, int E) {
  int e = blockIdx.x * 256 + threadIdx.x;
  if (e < E) {
    int d = dst[e];
    int pos = offsets[d] + atomicAdd(&cursor[d], 1);
    src_sorted[pos] = src[e];
  }
}

// ---------------- fused score + softmax + aggregate ----------------
// scores for 2 edges per lane (edges base+lane, base+lane+64)
__device__ __forceinline__ void score2(const _Float16* __restrict__ u_cat,
                                       const _Float16* svb, const _Float16* sw2,
                                       int s0, int s1, const float* b2v,
                                       float* ek0, float* ek1, bool v0, bool v1) {
  float acc0[8], acc1[8];
#pragma unroll
  for (int k = 0; k < 8; k++) { acc0[k] = b2v[k]; acc1[k] = b2v[k]; }
  const F16x8* up0 = (const F16x8*)(u_cat + (size_t)s0 * 256);
  const F16x8* up1 = (const F16x8*)(u_cat + (size_t)s1 * 256);
#pragma unroll
  for (int rel = 0; rel < 2; rel++) {
    const F16x8* vb = (const F16x8*)(svb + rel * 128);
#pragma unroll
    for (int c = 0; c < 16; c++) {
      F16x8 ua = up0[rel * 16 + c];
      F16x8 ub = up1[rel * 16 + c];
      F16x8 vv = vb[c];
      f16x2 ha0 = relu2(ua.a + vv.a), ha1 = relu2(ua.b + vv.b);
      f16x2 ha2 = relu2(ua.c + vv.c), ha3 = relu2(ua.d + vv.d);
      f16x2 hb0 = relu2(ub.a + vv.a), hb1 = relu2(ub.b + vv.b);
      f16x2 hb2 = relu2(ub.c + vv.c), hb3 = relu2(ub.d + vv.d);
      const f16x2* wp = (const f16x2*)(sw2 + (rel * 16 + c) * 32);
#pragma unroll
      for (int k = 0; k < 4; k++) {
        f16x2 w0 = wp[k * 4 + 0], w1 = wp[k * 4 + 1], w2 = wp[k * 4 + 2], w3 = wp[k * 4 + 3];
        float t0 = acc0[rel * 4 + k];
        t0 = fdot2(ha0, w0, t0); t0 = fdot2(ha1, w1, t0);
        t0 = fdot2(ha2, w2, t0); t0 = fdot2(ha3, w3, t0);
        acc0[rel * 4 + k] = t0;
        float t1 = acc1[rel * 4 + k];
        t1 = fdot2(hb0, w0, t1); t1 = fdot2(hb1, w1, t1);
        t1 = fdot2(hb2, w2, t1); t1 = fdot2(hb3, w3, t1);
        acc1[rel * 4 + k] = t1;
      }
    }
  }
#pragma unroll
  for (int k = 0; k < 8; k++) {
    float x = acc0[k]; x = x > 0.f ? x : 0.01f * x;
    ek0[k] = v0 ? __expf(x) : 0.f;
    float y = acc1[k]; y = y > 0.f ? y : 0.01f * y;
    ek1[k] = v1 ? __expf(y) : 0.f;
  }
}

__launch_bounds__(256)
__global__ void fused_kernel(const _Float16* __restrict__ u_cat, const _Float16* __restrict__ v_cat,
                             const _Float16* __restrict__ h16,
                             const int* __restrict__ src_sorted, const int* __restrict__ offsets,
                             const float* __restrict__ b1a, const float* __restrict__ b1b,
                             const float* __restrict__ w2a, const float* __restrict__ w2b,
                             const float* __restrict__ b2a, const float* __restrict__ b2b,
                             float* __restrict__ out, int N) {
  __shared__ _Float16 s_w2[1024];          // [rel][c][k][jj] : ((rel*16+c)*4+k)*8+jj
  __shared__ _Float16 s_vb[4][256];        // per-wave v[dst]+b1
  __shared__ float    s_ek[4][128][8];     // per-wave un-normalized exp weights
  __shared__ int      s_src[4][128];

  int tid = threadIdx.x, lane = tid & 63, w = tid >> 6;
  for (int i = tid; i < 1024; i += 256) {
    int rel = i >> 9, r = i & 511, c = r >> 5, k = (r >> 3) & 3, jj = r & 7;
    int j = c * 8 + jj;
    float val = rel ? w2b[j * NH + k] : w2a[j * NH + k];
    s_w2[i] = (_Float16)val;
  }
  int wid = blockIdx.x * 4 + w;
  int off0 = 0, deg = 0;
  if (wid < N) {
    off0 = offsets[wid];
    deg = offsets[wid + 1] - off0;
    for (int jj = lane; jj < 256; jj += 64) {
      float b1v = jj < 128 ? b1a[jj] : b1b[jj - 128];
      s_vb[w][jj] = (_Float16)((float)v_cat[(size_t)wid * 256 + jj] + b1v);
    }
  }
  __syncthreads();
  if (wid >= N) return;

  float* op = out + (size_t)wid * 512;
  if (deg == 0) {
#pragma unroll
    for (int k = 0; k < 4; k++) { op[k * 128 + lane] = 0.f; op[k * 128 + 64 + lane] = 0.f; }
    return;
  }

  float b2v[8];
#pragma unroll
  for (int k = 0; k < 8; k++) b2v[k] = k < 4 ? b2a[k] : b2b[k - 4];

  float accO[8] = {0, 0, 0, 0, 0, 0, 0, 0};
  float ssum[8];

  if (deg <= 128) {
    bool v0 = lane < deg, v1 = lane + 64 < deg;
    int s0 = v0 ? src_sorted[off0 + lane] : 0;
    int s1 = v1 ? src_sorted[off0 + lane + 64] : 0;
    float ek0[8], ek1[8];
    score2(u_cat, &s_vb[w][0], s_w2, s0, s1, b2v, ek0, ek1, v0, v1);
#pragma unroll
    for (int k = 0; k < 8; k++) {
      float t = ek0[k] + ek1[k];
#pragma unroll
      for (int o = 32; o >= 1; o >>= 1) t += __shfl_xor(t, o);
      ssum[k] = t;
    }
    *(float4*)&s_ek[w][lane][0] = make_float4(ek0[0], ek0[1], ek0[2], ek0[3]);
    *(float4*)&s_ek[w][lane][4] = make_float4(ek0[4], ek0[5], ek0[6], ek0[7]);
    *(float4*)&s_ek[w][lane + 64][0] = make_float4(ek1[0], ek1[1], ek1[2], ek1[3]);
    *(float4*)&s_ek[w][lane + 64][4] = make_float4(ek1[4], ek1[5], ek1[6], ek1[7]);
    s_src[w][lane] = s0; s_src[w][lane + 64] = s1;
    // same-wave LDS produce->consume; compiler inserts lgkmcnt waits
    int jj = 0;
    for (; jj + 2 <= deg; jj += 2) {
      float4 ea0 = *(float4*)&s_ek[w][jj][0];
      float4 ea1 = *(float4*)&s_ek[w][jj][4];
      float4 eb0 = *(float4*)&s_ek[w][jj + 1][0];
      float4 eb1 = *(float4*)&s_ek[w][jj + 1][4];
      int sa = s_src[w][jj], sb = s_src[w][jj + 1];
      float hva = (float)h16[(size_t)sa * DH + lane];
      float hvb = (float)h16[(size_t)sb * DH + lane];
      accO[0] = fmaf(ea0.x, hva, accO[0]); accO[1] = fmaf(ea0.y, hva, accO[1]);
      accO[2] = fmaf(ea0.z, hva, accO[2]); accO[3] = fmaf(ea0.w, hva, accO[3]);
      accO[4] = fmaf(ea1.x, hva, accO[4]); accO[5] = fmaf(ea1.y, hva, accO[5]);
      accO[6] = fmaf(ea1.z, hva, accO[6]); accO[7] = fmaf(ea1.w, hva, accO[7]);
      accO[0] = fmaf(eb0.x, hvb, accO[0]); accO[1] = fmaf(eb0.y, hvb, accO[1]);
      accO[2] = fmaf(eb0.z, hvb, accO[2]); accO[3] = fmaf(eb0.w, hvb, accO[3]);
      accO[4] = fmaf(eb1.x, hvb, accO[4]); accO[5] = fmaf(eb1.y, hvb, accO[5]);
      accO[6] = fmaf(eb1.z, hvb, accO[6]); accO[7] = fmaf(eb1.w, hvb, accO[7]);
    }
    if (jj < deg) {
      float4 ea0 = *(float4*)&s_ek[w][jj][0];
      float4 ea1 = *(float4*)&s_ek[w][jj][4];
      int sa = s_src[w][jj];
      float hva = (float)h16[(size_t)sa * DH + lane];
      accO[0] = fmaf(ea0.x, hva, accO[0]); accO[1] = fmaf(ea0.y, hva, accO[1]);
      accO[2] = fmaf(ea0.z, hva, accO[2]); accO[3] = fmaf(ea0.w, hva, accO[3]);
      accO[4] = fmaf(ea1.x, hva, accO[4]); accO[5] = fmaf(ea1.y, hva, accO[5]);
      accO[6] = fmaf(ea1.z, hva, accO[6]); accO[7] = fmaf(ea1.w, hva, accO[7]);
    }
  } else {
    // generic path for deg > 128 (rare/never for this data): two passes, recompute
#pragma unroll
    for (int k = 0; k < 8; k++) ssum[k] = 0.f;
    for (int base = 0; base < deg; base += 128) {
      bool v0 = base + lane < deg, v1 = base + lane + 64 < deg;
      int s0 = v0 ? src_sorted[off0 + base + lane] : 0;
      int s1 = v1 ? src_sorted[off0 + base + lane + 64] : 0;
      float ek0[8], ek1[8];
      score2(u_cat, &s_vb[w][0], s_w2, s0, s1, b2v, ek0, ek1, v0, v1);
#pragma unroll
      for (int k = 0; k < 8; k++) {
        float t = ek0[k] + ek1[k];
#pragma unroll
        for (int o = 32; o >= 1; o >>= 1) t += __shfl_xor(t, o);
        ssum[k] += t;
      }
    }
    for (int base = 0; base < deg; base += 128) {
      bool v0 = base + lane < deg, v1 = base + lane + 64 < deg;
      int s0 = v0 ? src_sorted[off0 + base + lane] : 0;
      int s1 = v1 ? src_sorted[off0 + base + lane + 64] : 0;
      float ek0[8], ek1[8];
      score2(u_cat, &s_vb[w][0], s_w2, s0, s1, b2v, ek0, ek1, v0, v1);
      *(float4*)&s_ek[w][lane][0] = make_float4(ek0[0], ek0[1], ek0[2], ek0[3]);
      *(float4*)&s_ek[w][lane][4] = make_float4(ek0[4], ek0[5], ek0[6], ek0[7]);
      *(float4*)&s_ek[w][lane + 64][0] = make_float4(ek1[0], ek1[1], ek1[2], ek1[3]);
      *(float4*)&s_ek[w][lane + 64][4] = make_float4(ek1[4], ek1[5], ek1[6], ek1[7]);
      s_src[w][lane] = s0; s_src[w][lane + 64] = s1;
      int cnt = min(128, deg - base);
      for (int jj = 0; jj < cnt; jj++) {
        float4 ea0 = *(float4*)&s_ek[w][jj][0];
        float4 ea1 = *(float4*)&s_ek[w][jj][4];
        int sa = s_src[w][jj];
        float hva = (float)h16[(size_t)sa * DH + lane];
        accO[0] = fmaf(ea0.x, hva, accO[0]); accO[1] = fmaf(ea0.y, hva, accO[1]);
        accO[2] = fmaf(ea0.z, hva, accO[2]); accO[3] = fmaf(ea0.w, hva, accO[3]);
        accO[4] = fmaf(ea1.x, hva, accO[4]); accO[5] = fmaf(ea1.y, hva, accO[5]);
        accO[6] = fmaf(ea1.z, hva, accO[6]); accO[7] = fmaf(ea1.w, hva, accO[7]);
      }
    }
  }

#pragma unroll
  for (int k = 0; k < 8; k++) {
    float rsv = 1.f / ssum[k];
    int col = k < 4 ? k * 128 + lane : (k - 4) * 128 + 64 + lane;
    op[col] = accO[k] * rsv;
  }
}

extern "C" void kernel_launch(void* const* d_in, const int* in_sizes, int n_in,
                              void* d_out, int out_size, void* d_ws, size_t ws_size,
                              hipStream_t stream) {
  const float* h      = (const float*)d_in[0];
  const float* pca    = (const float*)d_in[1];
  const float* pimg   = (const float*)d_in[2];
  const float* pca_w1 = (const float*)d_in[3];
  const float* pca_b1 = (const float*)d_in[4];
  const float* pca_w2 = (const float*)d_in[5];
  const float* pca_b2 = (const float*)d_in[6];
  const float* pi_w1  = (const float*)d_in[7];
  const float* pi_b1  = (const float*)d_in[8];
  const float* pi_w2  = (const float*)d_in[9];
  const float* pi_b2  = (const float*)d_in[10];
  const int*   src    = (const int*)d_in[11];
  const int*   dst    = (const int*)d_in[12];
  int N = in_sizes[0] / 64;
  int E = in_sizes[11];
  float* out = (float*)d_out;

  char* ws = (char*)d_ws;
  size_t o = 0;
  auto alloc = [&](size_t bytes) { void* p = ws + o; o += (bytes + 255) & ~(size_t)255; return p; };
  _Float16* u_cat = (_Float16*)alloc((size_t)N * 256 * 2);
  _Float16* v_cat = (_Float16*)alloc((size_t)N * 256 * 2);
  _Float16* h16   = (_Float16*)alloc((size_t)N * 64 * 2);
  int* counts  = (int*)alloc((size_t)N * 4);
  int* cursor  = (int*)alloc((size_t)N * 4);
  int* offsets = (int*)alloc((size_t)(N + 1) * 4);
  int* bsums   = (int*)alloc(1024 * 4);
  int* bpre    = (int*)alloc(1024 * 4);
  int* src_sorted = (int*)alloc((size_t)E * 4);

  hipMemsetAsync(counts, 0, (size_t)N * 4, stream);
  hipMemsetAsync(cursor, 0, (size_t)N * 4, stream);

  uv_kernel<64, 32><<<(N + 31) / 32, 256, 0, stream>>>(pca, pca_w1, u_cat, v_cat, 0, N);
  uv_kernel<32, 32><<<(N + 31) / 32, 256, 0, stream>>>(pimg, pi_w1, u_cat, v_cat, 128, N);
  h16_kernel<<<((N * 64) / 4 + 255) / 256, 256, 0, stream>>>(h, h16, N * 64);
  count_kernel<<<(E + 255) / 256, 256, 0, stream>>>(dst, counts, E);
  int NB = (N + 1023) / 1024;
  scan1_kernel<<<NB, 256, 0, stream>>>(counts, bsums, N);
  scan2_kernel<<<1, 1024, 0, stream>>>(bsums, bpre, offsets, NB, N, E);
  scan3_kernel<<<NB, 256, 0, stream>>>(counts, bpre, offsets, N);
  fill_kernel<<<(E + 255) / 256, 256, 0, stream>>>(src, dst, offsets, cursor, src_sorted, E);
  fused_kernel<<<(N + 3) / 4, 256, 0, stream>>>(u_cat, v_cat, h16, src_sorted, offsets,
                                                pca_b1, pi_b1, pca_w2, pi_w2, pca_b2, pi_b2,
                                                out, N);
}

// Round 3
// 486.623 us; speedup vs baseline: 1.3619x; 1.3619x over previous
//
#include <hip/hip_runtime.h>
#include <hip/hip_fp16.h>

constexpr int HID = 128;
constexpr int DH  = 64;

typedef _Float16 f16x2 __attribute__((ext_vector_type(2)));
struct F16x8 { f16x2 a, b, c, d; };   // 16 bytes

__device__ __forceinline__ float fdot2(f16x2 a, f16x2 b, float c) {
#if __has_builtin(__builtin_amdgcn_fdot2)
  return __builtin_amdgcn_fdot2(a, b, c, false);
#else
  return c + (float)a[0] * (float)b[0] + (float)a[1] * (float)b[1];
#endif
}

__device__ __forceinline__ f16x2 relu2(f16x2 x) {
  f16x2 z = {(_Float16)0, (_Float16)0};
#if __has_builtin(__builtin_elementwise_max)
  return __builtin_elementwise_max(x, z);
#else
  f16x2 r; r[0] = x[0] > z[0] ? x[0] : z[0]; r[1] = x[1] > z[1] ? x[1] : z[1]; return r;
#endif
}

// ---------------- uv precompute: u = feat @ W1_top, v = feat @ W1_bot + b1 ----------------
// concatenated tables: u_cat[n*256 + roff + j], roff = 0 (pca) / 128 (pimg)
template<int F, int NB>
__launch_bounds__(256)
__global__ void uv_kernel(const float* __restrict__ feat, const float* __restrict__ w1,
                          const float* __restrict__ b1,
                          _Float16* __restrict__ u_cat, _Float16* __restrict__ v_cat,
                          int roff, int N) {
  __shared__ float sfeat[NB][F + 1];
  int nb = blockIdx.x * NB;
  for (int i = threadIdx.x; i < NB * F; i += 256) {
    int n = i / F, k = i - n * F;
    int gn = nb + n;
    sfeat[n][k] = (gn < N) ? feat[(size_t)gn * F + k] : 0.f;
  }
  __syncthreads();
  int j = threadIdx.x & 127;
  int g = threadIdx.x >> 7;           // 0..1
  constexpr int NPT = NB / 2;
  float ua[NPT], va[NPT];
#pragma unroll
  for (int i = 0; i < NPT; i++) { ua[i] = 0.f; va[i] = 0.f; }
  for (int k = 0; k < F; k++) {
    float wu = w1[k * HID + j];
    float wv = w1[(F + k) * HID + j];
#pragma unroll
    for (int i = 0; i < NPT; i++) {
      float f = sfeat[g * NPT + i][k];
      ua[i] = fmaf(f, wu, ua[i]);
      va[i] = fmaf(f, wv, va[i]);
    }
  }
  float b1v = b1[j];
#pragma unroll
  for (int i = 0; i < NPT; i++) {
    int gn = nb + g * NPT + i;
    if (gn < N) {
      u_cat[(size_t)gn * 256 + roff + j] = (_Float16)ua[i];
      v_cat[(size_t)gn * 256 + roff + j] = (_Float16)(va[i] + b1v);
    }
  }
}

// ---------------- h -> fp16 copy ----------------
__global__ void h16_kernel(const float* __restrict__ h, _Float16* __restrict__ h16, int total) {
  int i = (blockIdx.x * 256 + threadIdx.x) * 4;
  if (i + 3 < total) {
    float4 v = *(const float4*)(h + i);
    h16[i] = (_Float16)v.x; h16[i + 1] = (_Float16)v.y;
    h16[i + 2] = (_Float16)v.z; h16[i + 3] = (_Float16)v.w;
  } else {
    for (int q = 0; q < 4; q++) if (i + q < total) h16[i + q] = (_Float16)h[i + q];
  }
}

// ---------------- CSR build ----------------
__global__ void count_kernel(const int* __restrict__ dst, int* __restrict__ counts, int E) {
  int e = blockIdx.x * 256 + threadIdx.x;
  if (e < E) atomicAdd(&counts[dst[e]], 1);
}

__launch_bounds__(256)
__global__ void scan1_kernel(const int* __restrict__ counts, int* __restrict__ bsums, int N) {
  int b = blockIdx.x, tid = threadIdx.x;
  int base = b * 1024 + tid * 4;
  int s = 0;
  if (base + 3 < N) {
    int4 v = *(const int4*)(counts + base);
    s = v.x + v.y + v.z + v.w;
  } else {
    for (int q = 0; q < 4; q++) { int idx = base + q; if (idx < N) s += counts[idx]; }
  }
#pragma unroll
  for (int o = 32; o >= 1; o >>= 1) s += __shfl_xor(s, o);
  __shared__ int ws[4];
  if ((tid & 63) == 0) ws[tid >> 6] = s;
  __syncthreads();
  if (tid == 0) bsums[b] = ws[0] + ws[1] + ws[2] + ws[3];
}

__launch_bounds__(1024)
__global__ void scan2_kernel(const int* __restrict__ bsums, int* __restrict__ bpre,
                             int* __restrict__ offsets, int NB, int N, int E) {
  int tid = threadIdx.x, lane = tid & 63, w = tid >> 6;
  int v = (tid < NB) ? bsums[tid] : 0;
  int incl = v;
#pragma unroll
  for (int o = 1; o < 64; o <<= 1) { int t = __shfl_up(incl, o); if (lane >= o) incl += t; }
  __shared__ int ws[16];
  if (lane == 63) ws[w] = incl;
  __syncthreads();
  int wpre = 0;
  for (int q = 0; q < w; q++) wpre += ws[q];
  if (tid < NB) bpre[tid] = wpre + incl - v;
  if (tid == 0) offsets[N] = E;
}

__launch_bounds__(256)
__global__ void scan3_kernel(const int* __restrict__ counts, const int* __restrict__ bpre,
                             int* __restrict__ offsets, int N) {
  int b = blockIdx.x, tid = threadIdx.x, lane = tid & 63, w = tid >> 6;
  int base = b * 1024 + tid * 4;
  int c[4] = {0, 0, 0, 0};
  if (base + 3 < N) {
    int4 v = *(const int4*)(counts + base);
    c[0] = v.x; c[1] = v.y; c[2] = v.z; c[3] = v.w;
  } else {
    for (int q = 0; q < 4; q++) { int idx = base + q; if (idx < N) c[q] = counts[idx]; }
  }
  int s = c[0] + c[1] + c[2] + c[3];
  int incl = s;
#pragma unroll
  for (int o = 1; o < 64; o <<= 1) { int t = __shfl_up(incl, o); if (lane >= o) incl += t; }
  int excl = incl - s;
  __shared__ int ws[4];
  if (lane == 63) ws[w] = incl;
  __syncthreads();
  int wpre = 0;
  for (int q = 0; q < w; q++) wpre += ws[q];
  int off = bpre[b] + wpre + excl;
  for (int q = 0; q < 4; q++) {
    int idx = base + q;
    if (idx < N) offsets[idx] = off;
    off += c[q];
  }
}

__global__ void fill_kernel(const int* __restrict__ src, const int* __restrict__ dst,
                            const int* __restrict__ offsets, int* __restrict__ cursor,
                            int* __restrict__ src_sorted, int* __restrict__ dst_sorted, int E) {
  int e = blockIdx.x * 256 + threadIdx.x;
  if (e < E) {
    int d = dst[e];
    int pos = offsets[d] + atomicAdd(&cursor[d], 1);
    src_sorted[pos] = src[e];
    dst_sorted[pos] = d;
  }
}

// ---------------- dense per-edge scores -> ek = exp(leaky_relu(mlp)) ----------------
// 2 consecutive edges per lane (shares w2 LDS reads; consecutive edges often share dst row)
__launch_bounds__(256)
__global__ void score_kernel(const _Float16* __restrict__ u_cat, const _Float16* __restrict__ v_cat,
                             const int* __restrict__ src_sorted, const int* __restrict__ dst_sorted,
                             const float* __restrict__ w2a, const float* __restrict__ w2b,
                             const float* __restrict__ b2a, const float* __restrict__ b2b,
                             float* __restrict__ ek, int E) {
  __shared__ _Float16 s_w2[1024];   // [c(32)][k(4)][jj(8)] : 16B contiguous per (c,k)
  int tid = threadIdx.x;
  for (int i = tid; i < 1024; i += 256) {
    int c = i >> 5, k = (i >> 3) & 3, jj = i & 7;
    int rel = c >> 4, j = (c & 15) * 8 + jj;
    float val = rel ? w2b[j * 4 + k] : w2a[j * 4 + k];
    s_w2[i] = (_Float16)val;
  }
  __syncthreads();
  int base = (blockIdx.x * 256 + tid) * 2;
  if (base >= E) return;
  bool has2 = base + 1 < E;
  int s0 = src_sorted[base], d0 = dst_sorted[base];
  int s1 = has2 ? src_sorted[base + 1] : s0;
  int d1 = has2 ? dst_sorted[base + 1] : d0;

  float acc0[8], acc1[8];
#pragma unroll
  for (int k = 0; k < 4; k++) {
    float ba = b2a[k], bb = b2b[k];
    acc0[k] = ba; acc0[4 + k] = bb;
    acc1[k] = ba; acc1[4 + k] = bb;
  }
  const F16x8* u0 = (const F16x8*)(u_cat + (size_t)s0 * 256);
  const F16x8* u1 = (const F16x8*)(u_cat + (size_t)s1 * 256);
  const F16x8* v0 = (const F16x8*)(v_cat + (size_t)d0 * 256);
  const F16x8* v1 = (const F16x8*)(v_cat + (size_t)d1 * 256);
#pragma unroll
  for (int c = 0; c < 32; c++) {
    int ko = (c >> 4) << 2;           // 0 for pca, 4 for pimg
    F16x8 ua = u0[c], va = v0[c];
    F16x8 ub = u1[c], vb = v1[c];
    f16x2 ha0 = relu2(ua.a + va.a), ha1 = relu2(ua.b + va.b);
    f16x2 ha2 = relu2(ua.c + va.c), ha3 = relu2(ua.d + va.d);
    f16x2 hb0 = relu2(ub.a + vb.a), hb1 = relu2(ub.b + vb.b);
    f16x2 hb2 = relu2(ub.c + vb.c), hb3 = relu2(ub.d + vb.d);
    const f16x2* wp = (const f16x2*)(s_w2 + c * 32);
#pragma unroll
    for (int k = 0; k < 4; k++) {
      f16x2 w0 = wp[k * 4 + 0], w1 = wp[k * 4 + 1], w2v = wp[k * 4 + 2], w3 = wp[k * 4 + 3];
      float t0 = acc0[ko + k];
      t0 = fdot2(ha0, w0, t0); t0 = fdot2(ha1, w1, t0);
      t0 = fdot2(ha2, w2v, t0); t0 = fdot2(ha3, w3, t0);
      acc0[ko + k] = t0;
      float t1 = acc1[ko + k];
      t1 = fdot2(hb0, w0, t1); t1 = fdot2(hb1, w1, t1);
      t1 = fdot2(hb2, w2v, t1); t1 = fdot2(hb3, w3, t1);
      acc1[ko + k] = t1;
    }
  }
  float r0[8], r1[8];
#pragma unroll
  for (int k = 0; k < 8; k++) {
    float x = acc0[k]; x = x > 0.f ? x : 0.01f * x; r0[k] = __expf(x);
    float y = acc1[k]; y = y > 0.f ? y : 0.01f * y; r1[k] = __expf(y);
  }
  float* ep = ek + (size_t)base * 8;
  *(float4*)(ep + 0) = make_float4(r0[0], r0[1], r0[2], r0[3]);
  *(float4*)(ep + 4) = make_float4(r0[4], r0[5], r0[6], r0[7]);
  if (has2) {
    *(float4*)(ep + 8)  = make_float4(r1[0], r1[1], r1[2], r1[3]);
    *(float4*)(ep + 12) = make_float4(r1[4], r1[5], r1[6], r1[7]);
  }
}

// ---------------- softmax-normalize + aggregate: one wave per dst node, ONE pass ----------------
__launch_bounds__(256)
__global__ void agg_kernel(const float* __restrict__ ek, const int* __restrict__ src_sorted,
                           const int* __restrict__ offsets, const _Float16* __restrict__ h16,
                           float* __restrict__ out, int N) {
  int wid = blockIdx.x * 4 + (threadIdx.x >> 6);
  int lane = threadIdx.x & 63;
  if (wid >= N) return;
  int off0 = offsets[wid], off1 = offsets[wid + 1];
  int deg = off1 - off0;
  float* op = out + (size_t)wid * 512;
  if (deg == 0) {
#pragma unroll
    for (int k = 0; k < 4; k++) { op[k * 128 + lane] = 0.f; op[k * 128 + 64 + lane] = 0.f; }
    return;
  }
  float accO[8] = {0, 0, 0, 0, 0, 0, 0, 0};
  float ssum[8] = {0, 0, 0, 0, 0, 0, 0, 0};
  int jj = 0;
  for (; jj + 2 <= deg; jj += 2) {
    size_t e0 = (size_t)(off0 + jj);
    const float4* p0 = (const float4*)(ek + e0 * 8);
    float4 a0 = p0[0], a1 = p0[1], b0 = p0[2], b1 = p0[3];
    int sa = src_sorted[e0], sb = src_sorted[e0 + 1];
    float hva = (float)h16[(size_t)sa * DH + lane];
    float hvb = (float)h16[(size_t)sb * DH + lane];
    accO[0] = fmaf(a0.x, hva, accO[0]); accO[1] = fmaf(a0.y, hva, accO[1]);
    accO[2] = fmaf(a0.z, hva, accO[2]); accO[3] = fmaf(a0.w, hva, accO[3]);
    accO[4] = fmaf(a1.x, hva, accO[4]); accO[5] = fmaf(a1.y, hva, accO[5]);
    accO[6] = fmaf(a1.z, hva, accO[6]); accO[7] = fmaf(a1.w, hva, accO[7]);
    accO[0] = fmaf(b0.x, hvb, accO[0]); accO[1] = fmaf(b0.y, hvb, accO[1]);
    accO[2] = fmaf(b0.z, hvb, accO[2]); accO[3] = fmaf(b0.w, hvb, accO[3]);
    accO[4] = fmaf(b1.x, hvb, accO[4]); accO[5] = fmaf(b1.y, hvb, accO[5]);
    accO[6] = fmaf(b1.z, hvb, accO[6]); accO[7] = fmaf(b1.w, hvb, accO[7]);
    ssum[0] += a0.x + b0.x; ssum[1] += a0.y + b0.y;
    ssum[2] += a0.z + b0.z; ssum[3] += a0.w + b0.w;
    ssum[4] += a1.x + b1.x; ssum[5] += a1.y + b1.y;
    ssum[6] += a1.z + b1.z; ssum[7] += a1.w + b1.w;
  }
  if (jj < deg) {
    size_t e0 = (size_t)(off0 + jj);
    const float4* p0 = (const float4*)(ek + e0 * 8);
    float4 a0 = p0[0], a1 = p0[1];
    int sa = src_sorted[e0];
    float hva = (float)h16[(size_t)sa * DH + lane];
    accO[0] = fmaf(a0.x, hva, accO[0]); accO[1] = fmaf(a0.y, hva, accO[1]);
    accO[2] = fmaf(a0.z, hva, accO[2]); accO[3] = fmaf(a0.w, hva, accO[3]);
    accO[4] = fmaf(a1.x, hva, accO[4]); accO[5] = fmaf(a1.y, hva, accO[5]);
    accO[6] = fmaf(a1.z, hva, accO[6]); accO[7] = fmaf(a1.w, hva, accO[7]);
    ssum[0] += a0.x; ssum[1] += a0.y; ssum[2] += a0.z; ssum[3] += a0.w;
    ssum[4] += a1.x; ssum[5] += a1.y; ssum[6] += a1.z; ssum[7] += a1.w;
  }
#pragma unroll
  for (int k = 0; k < 8; k++) {
    float rsv = 1.f / ssum[k];
    int col = k < 4 ? k * 128 + lane : (k - 4) * 128 + 64 + lane;
    op[col] = accO[k] * rsv;
  }
}

extern "C" void kernel_launch(void* const* d_in, const int* in_sizes, int n_in,
                              void* d_out, int out_size, void* d_ws, size_t ws_size,
                              hipStream_t stream) {
  const float* h      = (const float*)d_in[0];
  const float* pca    = (const float*)d_in[1];
  const float* pimg   = (const float*)d_in[2];
  const float* pca_w1 = (const float*)d_in[3];
  const float* pca_b1 = (const float*)d_in[4];
  const float* pca_w2 = (const float*)d_in[5];
  const float* pca_b2 = (const float*)d_in[6];
  const float* pi_w1  = (const float*)d_in[7];
  const float* pi_b1  = (const float*)d_in[8];
  const float* pi_w2  = (const float*)d_in[9];
  const float* pi_b2  = (const float*)d_in[10];
  const int*   src    = (const int*)d_in[11];
  const int*   dst    = (const int*)d_in[12];
  int N = in_sizes[0] / 64;
  int E = in_sizes[11];
  float* out = (float*)d_out;

  char* ws = (char*)d_ws;
  size_t o = 0;
  auto alloc = [&](size_t bytes) { void* p = ws + o; o += (bytes + 255) & ~(size_t)255; return p; };
  _Float16* u_cat = (_Float16*)alloc((size_t)N * 256 * 2);
  _Float16* v_cat = (_Float16*)alloc((size_t)N * 256 * 2);
  _Float16* h16   = (_Float16*)alloc((size_t)N * 64 * 2);
  int* counts  = (int*)alloc((size_t)N * 4);
  int* cursor  = (int*)alloc((size_t)N * 4);
  int* offsets = (int*)alloc((size_t)(N + 1) * 4);
  int* bsums   = (int*)alloc(1024 * 4);
  int* bpre    = (int*)alloc(1024 * 4);
  int* src_sorted = (int*)alloc((size_t)E * 4);
  int* dst_sorted = (int*)alloc((size_t)E * 4);
  float* ek       = (float*)alloc((size_t)E * 8 * 4);

  hipMemsetAsync(counts, 0, (size_t)N * 4, stream);
  hipMemsetAsync(cursor, 0, (size_t)N * 4, stream);

  uv_kernel<64, 32><<<(N + 31) / 32, 256, 0, stream>>>(pca, pca_w1, pca_b1, u_cat, v_cat, 0, N);
  uv_kernel<32, 32><<<(N + 31) / 32, 256, 0, stream>>>(pimg, pi_w1, pi_b1, u_cat, v_cat, 128, N);
  h16_kernel<<<((N * 64) / 4 + 255) / 256, 256, 0, stream>>>(h, h16, N * 64);
  count_kernel<<<(E + 255) / 256, 256, 0, stream>>>(dst, counts, E);
  int NB = (N + 1023) / 1024;
  scan1_kernel<<<NB, 256, 0, stream>>>(counts, bsums, N);
  scan2_kernel<<<1, 1024, 0, stream>>>(bsums, bpre, offsets, NB, N, E);
  scan3_kernel<<<NB, 256, 0, stream>>>(counts, bpre, offsets, N);
  fill_kernel<<<(E + 255) / 256, 256, 0, stream>>>(src, dst, offsets, cursor, src_sorted, dst_sorted, E);
  score_kernel<<<(E / 2 + 255) / 256, 256, 0, stream>>>(u_cat, v_cat, src_sorted, dst_sorted,
                                                        pca_w2, pi_w2, pca_b2, pi_b2, ek, E);
  agg_kernel<<<(N + 3) / 4, 256, 0, stream>>>(ek, src_sorted, offsets, h16, out, N);
}

// Round 4
// 330.059 us; speedup vs baseline: 2.0079x; 1.4744x over previous
//
#include <hip/hip_runtime.h>
#include <hip/hip_fp16.h>

constexpr int HID = 128;
constexpr int DH  = 64;

typedef _Float16 f16x2 __attribute__((ext_vector_type(2)));
struct F16x8 { f16x2 a, b, c, d; };   // 16 bytes

__device__ __forceinline__ float fdot2(f16x2 a, f16x2 b, float c) {
#if __has_builtin(__builtin_amdgcn_fdot2)
  return __builtin_amdgcn_fdot2(a, b, c, false);
#else
  return c + (float)a[0] * (float)b[0] + (float)a[1] * (float)b[1];
#endif
}

__device__ __forceinline__ f16x2 relu2(f16x2 x) {
  f16x2 z = {(_Float16)0, (_Float16)0};
#if __has_builtin(__builtin_elementwise_max)
  return __builtin_elementwise_max(x, z);
#else
  f16x2 r; r[0] = x[0] > z[0] ? x[0] : z[0]; r[1] = x[1] > z[1] ? x[1] : z[1]; return r;
#endif
}

// ---------------- uv precompute: u = feat @ W1_top, v = feat @ W1_bot + b1 ----------------
// concatenated tables: u_cat[n*256 + roff + j], roff = 0 (pca) / 128 (pimg)
template<int F, int NB>
__launch_bounds__(256)
__global__ void uv_kernel(const float* __restrict__ feat, const float* __restrict__ w1,
                          const float* __restrict__ b1,
                          _Float16* __restrict__ u_cat, _Float16* __restrict__ v_cat,
                          int roff, int N) {
  __shared__ float sfeat[NB][F + 1];
  int nb = blockIdx.x * NB;
  for (int i = threadIdx.x; i < NB * F; i += 256) {
    int n = i / F, k = i - n * F;
    int gn = nb + n;
    sfeat[n][k] = (gn < N) ? feat[(size_t)gn * F + k] : 0.f;
  }
  __syncthreads();
  int j = threadIdx.x & 127;
  int g = threadIdx.x >> 7;           // 0..1
  constexpr int NPT = NB / 2;
  float ua[NPT], va[NPT];
#pragma unroll
  for (int i = 0; i < NPT; i++) { ua[i] = 0.f; va[i] = 0.f; }
  for (int k = 0; k < F; k++) {
    float wu = w1[k * HID + j];
    float wv = w1[(F + k) * HID + j];
#pragma unroll
    for (int i = 0; i < NPT; i++) {
      float f = sfeat[g * NPT + i][k];
      ua[i] = fmaf(f, wu, ua[i]);
      va[i] = fmaf(f, wv, va[i]);
    }
  }
  float b1v = b1[j];
#pragma unroll
  for (int i = 0; i < NPT; i++) {
    int gn = nb + g * NPT + i;
    if (gn < N) {
      u_cat[(size_t)gn * 256 + roff + j] = (_Float16)ua[i];
      v_cat[(size_t)gn * 256 + roff + j] = (_Float16)(va[i] + b1v);
    }
  }
}

// ---------------- h -> fp16 copy ----------------
__global__ void h16_kernel(const float* __restrict__ h, _Float16* __restrict__ h16, int total) {
  int i = (blockIdx.x * 256 + threadIdx.x) * 4;
  if (i + 3 < total) {
    float4 v = *(const float4*)(h + i);
    h16[i] = (_Float16)v.x; h16[i + 1] = (_Float16)v.y;
    h16[i + 2] = (_Float16)v.z; h16[i + 3] = (_Float16)v.w;
  } else {
    for (int q = 0; q < 4; q++) if (i + q < total) h16[i + q] = (_Float16)h[i + q];
  }
}

// ---------------- CSR build ----------------
__global__ void count_kernel(const int* __restrict__ dst, int* __restrict__ counts, int E) {
  int e = blockIdx.x * 256 + threadIdx.x;
  if (e < E) atomicAdd(&counts[dst[e]], 1);
}

__launch_bounds__(256)
__global__ void scan1_kernel(const int* __restrict__ counts, int* __restrict__ bsums, int N) {
  int b = blockIdx.x, tid = threadIdx.x;
  int base = b * 1024 + tid * 4;
  int s = 0;
  if (base + 3 < N) {
    int4 v = *(const int4*)(counts + base);
    s = v.x + v.y + v.z + v.w;
  } else {
    for (int q = 0; q < 4; q++) { int idx = base + q; if (idx < N) s += counts[idx]; }
  }
#pragma unroll
  for (int o = 32; o >= 1; o >>= 1) s += __shfl_xor(s, o);
  __shared__ int ws[4];
  if ((tid & 63) == 0) ws[tid >> 6] = s;
  __syncthreads();
  if (tid == 0) bsums[b] = ws[0] + ws[1] + ws[2] + ws[3];
}

__launch_bounds__(1024)
__global__ void scan2_kernel(const int* __restrict__ bsums, int* __restrict__ bpre,
                             int* __restrict__ offsets, int NB, int N, int E) {
  int tid = threadIdx.x, lane = tid & 63, w = tid >> 6;
  int v = (tid < NB) ? bsums[tid] : 0;
  int incl = v;
#pragma unroll
  for (int o = 1; o < 64; o <<= 1) { int t = __shfl_up(incl, o); if (lane >= o) incl += t; }
  __shared__ int ws[16];
  if (lane == 63) ws[w] = incl;
  __syncthreads();
  int wpre = 0;
  for (int q = 0; q < w; q++) wpre += ws[q];
  if (tid < NB) bpre[tid] = wpre + incl - v;
  if (tid == 0) offsets[N] = E;
}

__launch_bounds__(256)
__global__ void scan3_kernel(const int* __restrict__ counts, const int* __restrict__ bpre,
                             int* __restrict__ offsets, int N) {
  int b = blockIdx.x, tid = threadIdx.x, lane = tid & 63, w = tid >> 6;
  int base = b * 1024 + tid * 4;
  int c[4] = {0, 0, 0, 0};
  if (base + 3 < N) {
    int4 v = *(const int4*)(counts + base);
    c[0] = v.x; c[1] = v.y; c[2] = v.z; c[3] = v.w;
  } else {
    for (int q = 0; q < 4; q++) { int idx = base + q; if (idx < N) c[q] = counts[idx]; }
  }
  int s = c[0] + c[1] + c[2] + c[3];
  int incl = s;
#pragma unroll
  for (int o = 1; o < 64; o <<= 1) { int t = __shfl_up(incl, o); if (lane >= o) incl += t; }
  int excl = incl - s;
  __shared__ int ws[4];
  if (lane == 63) ws[w] = incl;
  __syncthreads();
  int wpre = 0;
  for (int q = 0; q < w; q++) wpre += ws[q];
  int off = bpre[b] + wpre + excl;
  for (int q = 0; q < 4; q++) {
    int idx = base + q;
    if (idx < N) offsets[idx] = off;
    off += c[q];
  }
}

__global__ void fill_kernel(const int* __restrict__ src, const int* __restrict__ dst,
                            const int* __restrict__ offsets, int* __restrict__ cursor,
                            int* __restrict__ src_sorted, int* __restrict__ dst_sorted, int E) {
  int e = blockIdx.x * 256 + threadIdx.x;
  if (e < E) {
    int d = dst[e];
    int pos = offsets[d] + atomicAdd(&cursor[d], 1);
    src_sorted[pos] = src[e];
    dst_sorted[pos] = d;
  }
}

// ---------------- dense per-edge scores -> ek = exp(leaky_relu(mlp)) ----------------
// ONE edge per lane; VGPR capped via launch_bounds for occupancy (round-3 lesson:
// 2 edges/lane + full unroll -> 256 VGPR -> 10% occupancy -> latency-bound)
__launch_bounds__(256, 4)
__global__ void score_kernel(const _Float16* __restrict__ u_cat, const _Float16* __restrict__ v_cat,
                             const int* __restrict__ src_sorted, const int* __restrict__ dst_sorted,
                             const float* __restrict__ w2a, const float* __restrict__ w2b,
                             const float* __restrict__ b2a, const float* __restrict__ b2b,
                             float* __restrict__ ek, int E) {
  __shared__ _Float16 s_w2[1024];   // [c(32)][k(4)][jj(8)] : 16B contiguous per (c,k)
  int tid = threadIdx.x;
  for (int i = tid; i < 1024; i += 256) {
    int c = i >> 5, k = (i >> 3) & 3, jj = i & 7;
    int rel = c >> 4, j = (c & 15) * 8 + jj;
    float val = rel ? w2b[j * 4 + k] : w2a[j * 4 + k];
    s_w2[i] = (_Float16)val;
  }
  __syncthreads();
  int e = blockIdx.x * 256 + tid;
  if (e >= E) return;
  int s = src_sorted[e], d = dst_sorted[e];

  float acc[8];
#pragma unroll
  for (int k = 0; k < 4; k++) { acc[k] = b2a[k]; acc[4 + k] = b2b[k]; }

  const F16x8* up = (const F16x8*)(u_cat + (size_t)s * 256);
  const F16x8* vp = (const F16x8*)(v_cat + (size_t)d * 256);
#pragma unroll 4
  for (int c = 0; c < 32; c++) {
    int ko = (c >> 4) << 2;           // 0 for pca, 4 for pimg
    F16x8 ua = up[c], va = vp[c];
    f16x2 h0 = relu2(ua.a + va.a), h1 = relu2(ua.b + va.b);
    f16x2 h2 = relu2(ua.c + va.c), h3 = relu2(ua.d + va.d);
    const f16x2* wp = (const f16x2*)(s_w2 + c * 32);
#pragma unroll
    for (int k = 0; k < 4; k++) {
      f16x2 w0 = wp[k * 4 + 0], w1 = wp[k * 4 + 1], w2v = wp[k * 4 + 2], w3 = wp[k * 4 + 3];
      float t = acc[ko + k];
      t = fdot2(h0, w0, t); t = fdot2(h1, w1, t);
      t = fdot2(h2, w2v, t); t = fdot2(h3, w3, t);
      acc[ko + k] = t;
    }
  }
  float r[8];
#pragma unroll
  for (int k = 0; k < 8; k++) {
    float x = acc[k]; x = x > 0.f ? x : 0.01f * x; r[k] = __expf(x);
  }
  float* ep = ek + (size_t)e * 8;
  *(float4*)(ep + 0) = make_float4(r[0], r[1], r[2], r[3]);
  *(float4*)(ep + 4) = make_float4(r[4], r[5], r[6], r[7]);
}

// ---------------- softmax-normalize + aggregate: one wave per dst node, ONE pass ----------------
__launch_bounds__(256)
__global__ void agg_kernel(const float* __restrict__ ek, const int* __restrict__ src_sorted,
                           const int* __restrict__ offsets, const _Float16* __restrict__ h16,
                           float* __restrict__ out, int N) {
  int wid = blockIdx.x * 4 + (threadIdx.x >> 6);
  int lane = threadIdx.x & 63;
  if (wid >= N) return;
  int off0 = offsets[wid], off1 = offsets[wid + 1];
  int deg = off1 - off0;
  float* op = out + (size_t)wid * 512;
  if (deg == 0) {
#pragma unroll
    for (int k = 0; k < 4; k++) { op[k * 128 + lane] = 0.f; op[k * 128 + 64 + lane] = 0.f; }
    return;
  }
  float accO[8] = {0, 0, 0, 0, 0, 0, 0, 0};
  float ssum[8] = {0, 0, 0, 0, 0, 0, 0, 0};
  int jj = 0;
  for (; jj + 2 <= deg; jj += 2) {
    size_t e0 = (size_t)(off0 + jj);
    const float4* p0 = (const float4*)(ek + e0 * 8);
    float4 a0 = p0[0], a1 = p0[1], b0 = p0[2], b1 = p0[3];
    int sa = src_sorted[e0], sb = src_sorted[e0 + 1];
    float hva = (float)h16[(size_t)sa * DH + lane];
    float hvb = (float)h16[(size_t)sb * DH + lane];
    accO[0] = fmaf(a0.x, hva, accO[0]); accO[1] = fmaf(a0.y, hva, accO[1]);
    accO[2] = fmaf(a0.z, hva, accO[2]); accO[3] = fmaf(a0.w, hva, accO[3]);
    accO[4] = fmaf(a1.x, hva, accO[4]); accO[5] = fmaf(a1.y, hva, accO[5]);
    accO[6] = fmaf(a1.z, hva, accO[6]); accO[7] = fmaf(a1.w, hva, accO[7]);
    accO[0] = fmaf(b0.x, hvb, accO[0]); accO[1] = fmaf(b0.y, hvb, accO[1]);
    accO[2] = fmaf(b0.z, hvb, accO[2]); accO[3] = fmaf(b0.w, hvb, accO[3]);
    accO[4] = fmaf(b1.x, hvb, accO[4]); accO[5] = fmaf(b1.y, hvb, accO[5]);
    accO[6] = fmaf(b1.z, hvb, accO[6]); accO[7] = fmaf(b1.w, hvb, accO[7]);
    ssum[0] += a0.x + b0.x; ssum[1] += a0.y + b0.y;
    ssum[2] += a0.z + b0.z; ssum[3] += a0.w + b0.w;
    ssum[4] += a1.x + b1.x; ssum[5] += a1.y + b1.y;
    ssum[6] += a1.z + b1.z; ssum[7] += a1.w + b1.w;
  }
  if (jj < deg) {
    size_t e0 = (size_t)(off0 + jj);
    const float4* p0 = (const float4*)(ek + e0 * 8);
    float4 a0 = p0[0], a1 = p0[1];
    int sa = src_sorted[e0];
    float hva = (float)h16[(size_t)sa * DH + lane];
    accO[0] = fmaf(a0.x, hva, accO[0]); accO[1] = fmaf(a0.y, hva, accO[1]);
    accO[2] = fmaf(a0.z, hva, accO[2]); accO[3] = fmaf(a0.w, hva, accO[3]);
    accO[4] = fmaf(a1.x, hva, accO[4]); accO[5] = fmaf(a1.y, hva, accO[5]);
    accO[6] = fmaf(a1.z, hva, accO[6]); accO[7] = fmaf(a1.w, hva, accO[7]);
    ssum[0] += a0.x; ssum[1] += a0.y; ssum[2] += a0.z; ssum[3] += a0.w;
    ssum[4] += a1.x; ssum[5] += a1.y; ssum[6] += a1.z; ssum[7] += a1.w;
  }
#pragma unroll
  for (int k = 0; k < 8; k++) {
    float rsv = 1.f / ssum[k];
    int col = k < 4 ? k * 128 + lane : (k - 4) * 128 + 64 + lane;
    op[col] = accO[k] * rsv;
  }
}

extern "C" void kernel_launch(void* const* d_in, const int* in_sizes, int n_in,
                              void* d_out, int out_size, void* d_ws, size_t ws_size,
                              hipStream_t stream) {
  const float* h      = (const float*)d_in[0];
  const float* pca    = (const float*)d_in[1];
  const float* pimg   = (const float*)d_in[2];
  const float* pca_w1 = (const float*)d_in[3];
  const float* pca_b1 = (const float*)d_in[4];
  const float* pca_w2 = (const float*)d_in[5];
  const float* pca_b2 = (const float*)d_in[6];
  const float* pi_w1  = (const float*)d_in[7];
  const float* pi_b1  = (const float*)d_in[8];
  const float* pi_w2  = (const float*)d_in[9];
  const float* pi_b2  = (const float*)d_in[10];
  const int*   src    = (const int*)d_in[11];
  const int*   dst    = (const int*)d_in[12];
  int N = in_sizes[0] / 64;
  int E = in_sizes[11];
  float* out = (float*)d_out;

  char* ws = (char*)d_ws;
  size_t o = 0;
  auto alloc = [&](size_t bytes) { void* p = ws + o; o += (bytes + 255) & ~(size_t)255; return p; };
  _Float16* u_cat = (_Float16*)alloc((size_t)N * 256 * 2);
  _Float16* v_cat = (_Float16*)alloc((size_t)N * 256 * 2);
  _Float16* h16   = (_Float16*)alloc((size_t)N * 64 * 2);
  int* counts  = (int*)alloc((size_t)N * 4);
  int* cursor  = (int*)alloc((size_t)N * 4);
  int* offsets = (int*)alloc((size_t)(N + 1) * 4);
  int* bsums   = (int*)alloc(1024 * 4);
  int* bpre    = (int*)alloc(1024 * 4);
  int* src_sorted = (int*)alloc((size_t)E * 4);
  int* dst_sorted = (int*)alloc((size_t)E * 4);
  float* ek       = (float*)alloc((size_t)E * 8 * 4);

  hipMemsetAsync(counts, 0, (size_t)N * 4, stream);
  hipMemsetAsync(cursor, 0, (size_t)N * 4, stream);

  uv_kernel<64, 32><<<(N + 31) / 32, 256, 0, stream>>>(pca, pca_w1, pca_b1, u_cat, v_cat, 0, N);
  uv_kernel<32, 32><<<(N + 31) / 32, 256, 0, stream>>>(pimg, pi_w1, pi_b1, u_cat, v_cat, 128, N);
  h16_kernel<<<((N * 64) / 4 + 255) / 256, 256, 0, stream>>>(h, h16, N * 64);
  count_kernel<<<(E + 255) / 256, 256, 0, stream>>>(dst, counts, E);
  int NB = (N + 1023) / 1024;
  scan1_kernel<<<NB, 256, 0, stream>>>(counts, bsums, N);
  scan2_kernel<<<1, 1024, 0, stream>>>(bsums, bpre, offsets, NB, N, E);
  scan3_kernel<<<NB, 256, 0, stream>>>(counts, bpre, offsets, N);
  fill_kernel<<<(E + 255) / 256, 256, 0, stream>>>(src, dst, offsets, cursor, src_sorted, dst_sorted, E);
  score_kernel<<<(E + 255) / 256, 256, 0, stream>>>(u_cat, v_cat, src_sorted, dst_sorted,
                                                    pca_w2, pi_w2, pca_b2, pi_b2, ek, E);
  agg_kernel<<<(N + 3) / 4, 256, 0, stream>>>(ek, src_sorted, offsets, h16, out, N);
}